// Round 5
// baseline (70.772 us; speedup 1.0000x reference)
//
#include <hip/hip_runtime.h>

// ColorHistogramLoss: soft histogram (Gaussian kernel, 64 bins) over
// pred/target (4,3,256,256) fp32, normalized, cumsum, mean |cdf diff|.
//
// v5 (resubmit — prior round failed on container acquisition, not kernel):
//   transposed lane-private LDS (h[wave][lane][84]) so a pixel's tap
//   window is CONSECUTIVE dwords -> 6x float2 (ds_read_b64/ds_write_b64)
//   RMW per pixel (12 LDS ops) instead of 22x b32. Branch-free even-
//   aligned 12-row window (w0=(i-5)&~1) covers bins i-5..i+5; weights by
//   ratio recurrence from the window edge. Lane stride 84 dwords -> start
//   bank 20l%32: 8 distinct bank-pairs per 8 lanes, 2-way alias = free.
//   v4 post-mortem: hist is LDS-issue-bound (~5.8cy/b32, 22 ops/px);
//   fills (harness d_ws poison, 41us) are the benchmark floor.
//
// Structure:
//   hist_kernel : 768 blocks x 128 thr (2 waves, 3 blocks/CU exact);
//                 transposed lane columns, staggered column reduce,
//                 plain store of per-block 64-bin partial to d_ws
//   final_kernel: 1 block x 768 thr (12 waves); sum 32 chunk partials
//                 (coalesced), wave scan -> cdf -> |diff| -> mean

#define BINS 64
#define NCH 12            // B*C = 4*3
#define HW 65536          // 256*256
#define BPC 32            // pixel-chunks (blocks) per channel-image
#define PIX_PER_BLOCK (HW / BPC)              // 2048
#define THREADS 128
#define PPT (PIX_PER_BLOCK / THREADS)         // 16 pixels per thread
#define ROWPAD 84         // dwords per lane column: 16B-aligned, bank-spread
#define NW (THREADS / 64) // 2 waves
#define WROWS 12          // even-aligned window rows (6 float2)

__device__ __forceinline__ float fast_exp2(float x) {
#if __has_builtin(__builtin_amdgcn_exp2f)
    return __builtin_amdgcn_exp2f(x);   // v_exp_f32
#else
    return exp2f(x);
#endif
}

// Window rows w0..w0+11 (w0 = (i-5)&~1, even; padded row = w0+6+s, 0..75).
// Weight for row w0+s: exp(-(f0-s)^2/2), f0 = xt-w0 in [4.5,6.5]
//   = A * B^s * CC[s];  A = exp(-f0^2/2), B = exp(f0)   (2x exp2/pixel)
// CC[s] = exp(-s^2/2) compile-time; P_s = A*B^s in [e^-21, e^51] fp32-safe.
__global__ __launch_bounds__(THREADS) void hist_kernel(
        const float* __restrict__ pred,
        const float* __restrict__ target,
        float* __restrict__ part_out) {
    constexpr float CC[WROWS] = {
        1.0f,
        6.0653065971263342e-01f, 1.3533528323661270e-01f,
        1.1108996538242306e-02f, 3.3546262790251185e-04f,
        3.7266531720786709e-06f, 1.5229979744712628e-08f,
        2.2897348456455526e-11f, 1.2664165549094176e-14f,
        2.5767571091549810e-18f, 1.9287498479639178e-22f,
        5.3204056952276910e-27f };

    const int blk   = blockIdx.x;
    const int ch    = blk / BPC;        // 0..23 (0..11 pred, 12..23 target)
    const int chunk = blk % BPC;
    const float* src = (ch < NCH) ? (pred + (size_t)ch * HW)
                                  : (target + (size_t)(ch - NCH) * HW);

    __shared__ float h[NW][64][ROWPAD];   // 43008 B, lane-private columns
    __shared__ float part[NW][BINS];

    const int wv   = threadIdx.x >> 6;
    const int lane = threadIdx.x & 63;

    // zero h: 10752 dwords = 2688 float4 / 128 thr = 21 each
    {
        float4* hz = (float4*)&h[0][0][0];
        #pragma unroll
        for (int t = 0; t < NW * 64 * ROWPAD / 4 / THREADS; ++t)
            hz[threadIdx.x + t * THREADS] = make_float4(0.f, 0.f, 0.f, 0.f);
    }
    __syncthreads();

    // 512 float4 per block; thread t loads f4[t + k*128], k=0..3 (coalesced).
    const float4* src4 = (const float4*)(src + chunk * PIX_PER_BLOCK);
    float4 a = src4[threadIdx.x];
    float4 b = src4[threadIdx.x + THREADS];
    float4 c = src4[threadIdx.x + 2 * THREADS];
    float4 d = src4[threadIdx.x + 3 * THREADS];
    float px[PPT] = {a.x, a.y, a.z, a.w, b.x, b.y, b.z, b.w,
                     c.x, c.y, c.z, c.w, d.x, d.y, d.z, d.w};

    const float L  = 1.4426950408889634f;    // log2(e)
    const float L2 = 0.7213475204444817f;    // log2(e)/2

    float2* lane2 = reinterpret_cast<float2*>(&h[wv][lane][0]);  // 42 float2

    #pragma unroll
    for (int p = 0; p < PPT; ++p) {
        float xt = px[p] * 64.0f - 0.5f;       // bin-center units
        float fi = rintf(xt);
        fi = fminf(fmaxf(fi, 0.0f), 63.0f);    // defensive clamp
        int   i  = (int)fi;                    // nearest bin, 0..63
        int   w0 = (i - 5) & ~1;               // even window start, -6..58
        float f0 = xt - (float)w0;             // [4.5, 6.5]
        float A  = fast_exp2(-L2 * f0 * f0);
        float B  = fast_exp2(L * f0);
        float P  = A;
        int   b2 = (w0 + 6) >> 1;              // float2 index 0..32
        #pragma unroll
        for (int s2 = 0; s2 < WROWS / 2; ++s2) {
            float2 v = lane2[b2 + s2];                 // ds_read_b64
            v.x = fmaf(P, CC[2 * s2], v.x);     P *= B;
            v.y = fmaf(P, CC[2 * s2 + 1], v.y); P *= B;
            lane2[b2 + s2] = v;                        // ds_write_b64
        }
    }

    __syncthreads();

    // Per-wave column reduce: lane j sums 64 lane-columns at padded row j+6.
    // bank = (21j + 20cc) % 32, gcd(21,32)=1 -> 2-way alias, free.
    {
        const int j = lane;
        float s = 0.0f;
        #pragma unroll
        for (int cc = 0; cc < 64; ++cc)
            s += h[wv][(j + cc) & 63][j + 6];
        part[wv][j] = s;
    }
    __syncthreads();
    if (threadIdx.x < BINS) {
        const int j = threadIdx.x;
        part_out[blk * BINS + j] = part[0][j] + part[1][j];  // plain store
    }
}

__global__ __launch_bounds__(NCH * 64) void final_kernel(
        const float* __restrict__ part, float* __restrict__ out) {
    const int w    = threadIdx.x >> 6;   // 0..11 -> (b,c) channel
    const int lane = threadIdx.x & 63;   // bin

    // sum the 32 chunk-partials for pred and target (coalesced per c).
    float ph = 0.0f, th = 0.0f;
    #pragma unroll
    for (int c = 0; c < BPC; ++c) {
        ph += part[(w * BPC + c) * BINS + lane];
        th += part[((NCH + w) * BPC + c) * BINS + lane];
    }

    // inclusive scan over bins (wave64 shfl_up)
    float ps = ph, ts = th;
    #pragma unroll
    for (int d = 1; d < 64; d <<= 1) {
        float a = __shfl_up(ps, d, 64);
        float b = __shfl_up(ts, d, 64);
        if (lane >= d) { ps += a; ts += b; }
    }
    float ptot = __shfl(ps, 63, 64);
    float ttot = __shfl(ts, 63, 64);
    float pc = ps / (ptot + 1e-8f);
    float tc = ts / (ttot + 1e-8f);
    float dv = fabsf(pc - tc);

    // wave reduce
    #pragma unroll
    for (int k = 32; k >= 1; k >>= 1) dv += __shfl_xor(dv, k, 64);

    __shared__ float warr[NCH];
    if (lane == 0) warr[w] = dv;
    __syncthreads();
    if (threadIdx.x == 0) {
        float s = 0.0f;
        #pragma unroll
        for (int i = 0; i < NCH; ++i) s += warr[i];
        out[0] = s / (float)(NCH * BINS);
    }
}

extern "C" void kernel_launch(void* const* d_in, const int* in_sizes, int n_in,
                              void* d_out, int out_size, void* d_ws, size_t ws_size,
                              hipStream_t stream) {
    const float* pred   = (const float*)d_in[0];
    const float* target = (const float*)d_in[1];
    float* part = (float*)d_ws;          // 768*64 floats = 196 KB partials
    float* out  = (float*)d_out;

    hist_kernel<<<dim3(2 * NCH * BPC), dim3(THREADS), 0, stream>>>(
        pred, target, part);
    final_kernel<<<dim3(1), dim3(NCH * 64), 0, stream>>>(part, out);
}

// Round 6
// 64.836 us; speedup vs baseline: 1.0916x; 1.0916x over previous
//
#include <hip/hip_runtime.h>

// ColorHistogramLoss: soft histogram (Gaussian kernel, 64 bins) over
// pred/target (4,3,256,256) fp32, normalized, cumsum, mean |cdf diff|.
//
// v6: back to v4's row-major lane-private LDS (bank = lane%32, DATA-
//   INDEPENDENT conflict-free — v5 post-mortem: any transposed/b64 layout
//   has data-dependent bank clumping, ~4x cost). Levers vs v4:
//   (1) R=4 window: 9 taps -> 18 b32 RMW ops/px (was 13 taps/26 ops);
//       excluded mass |k|>=5 is ~3e-6 relative -> ~2e-6 on final scalar.
//   (2) batched RMW: 9 ds_read (1 addr + offset:t*256) -> wait -> 9 fma
//       -> 9 ds_write; shortens per-pixel serial chain.
//
// Structure:
//   hist_kernel : 768 blocks x 128 thr (2 waves, 3 blocks/CU exact);
//                 h[wave][72][64] row-major, staggered column reduce,
//                 plain store of per-block 64-bin partial to d_ws
//   final_kernel: 1 block x 768 thr (12 waves); sum 32 chunk partials
//                 (coalesced), wave scan -> cdf -> |diff| -> mean

#define BINS 64
#define NCH 12            // B*C = 4*3
#define HW 65536          // 256*256
#define BPC 32            // pixel-chunks (blocks) per channel-image
#define PIX_PER_BLOCK (HW / BPC)              // 2048
#define THREADS 128
#define PPT (PIX_PER_BLOCK / THREADS)         // 16 pixels per thread
#define R 4               // Gaussian support radius (edge weight e^-8)
#define WIN (2 * R + 1)   // 9 taps
#define PADBINS (BINS + 2 * R)   // 72 rows: row = bin + R, bins -4..67
#define NW (THREADS / 64) // 2 waves

__device__ __forceinline__ float fast_exp2(float x) {
#if __has_builtin(__builtin_amdgcn_exp2f)
    return __builtin_amdgcn_exp2f(x);   // v_exp_f32
#else
    return exp2f(x);
#endif
}

// weight for bin i-R+t (t=0..8): exp(-(f-(t-R))^2/2) = CK[t] * P_t,
//   P_0 = exp(-f^2/2 - R*f)  (one exp2)    B = exp(f)  (one exp2)
//   P_{t+1} = P_t * B ;  CK[t] = exp(-(t-R)^2/2)  (compile-time)
// P_t = exp(-f^2/2 + (t-R)f) in [e^-2.125, e^2] — tiny fp32 range.
__global__ __launch_bounds__(THREADS) void hist_kernel(
        const float* __restrict__ pred,
        const float* __restrict__ target,
        float* __restrict__ part_out) {
    constexpr float CK[WIN] = {
        3.3546262790251185e-04f, 1.1108996538242306e-02f,
        1.3533528323661270e-01f, 6.0653065971263342e-01f, 1.0f,
        6.0653065971263342e-01f, 1.3533528323661270e-01f,
        1.1108996538242306e-02f, 3.3546262790251185e-04f };

    const int blk   = blockIdx.x;
    const int ch    = blk / BPC;        // 0..23 (0..11 pred, 12..23 target)
    const int chunk = blk % BPC;
    const float* src = (ch < NCH) ? (pred + (size_t)ch * HW)
                                  : (target + (size_t)(ch - NCH) * HW);

    // row-major lane-private columns: bank = lane%32 for every tap row,
    // conflict-free (2-way) independent of pixel data. No atomics.
    __shared__ float h[NW][PADBINS][64];   // 36864 B
    __shared__ float part[NW][BINS];

    const int wv   = threadIdx.x >> 6;
    const int lane = threadIdx.x & 63;

    // zero h: 9216 dwords = 2304 float4 / 128 thr = 18 each (exact)
    {
        float4* hz = (float4*)&h[0][0][0];
        #pragma unroll
        for (int t = 0; t < NW * PADBINS * 64 / 4 / THREADS; ++t)
            hz[threadIdx.x + t * THREADS] = make_float4(0.f, 0.f, 0.f, 0.f);
    }
    __syncthreads();

    // 512 float4 per block; thread t loads f4[t + k*128], k=0..3 (coalesced).
    const float4* src4 = (const float4*)(src + chunk * PIX_PER_BLOCK);
    float4 a = src4[threadIdx.x];
    float4 b = src4[threadIdx.x + THREADS];
    float4 c = src4[threadIdx.x + 2 * THREADS];
    float4 d = src4[threadIdx.x + 3 * THREADS];
    float px[PPT] = {a.x, a.y, a.z, a.w, b.x, b.y, b.z, b.w,
                     c.x, c.y, c.z, c.w, d.x, d.y, d.z, d.w};

    const float L  = 1.4426950408889634f;    // log2(e)
    const float L2 = 0.7213475204444817f;    // log2(e)/2

    #pragma unroll
    for (int p = 0; p < PPT; ++p) {
        float xt = px[p] * 64.0f - 0.5f;       // bin-center units
        float fi = rintf(xt);
        fi = fminf(fmaxf(fi, 0.0f), 63.0f);    // defensive clamp
        float f  = xt - fi;                    // [-0.5, 0.5]
        int   i  = (int)fi;                    // nearest bin -> rows i..i+8
        float P  = fast_exp2(-L2 * f * f - (float)R * L * f);
        float B  = fast_exp2(L * f);

        // batched RMW: 9 reads (one vaddr, offset:t*256) -> 9 fma -> 9 writes
        float v[WIN];
        #pragma unroll
        for (int t = 0; t < WIN; ++t) v[t] = h[wv][i + t][lane];
        #pragma unroll
        for (int t = 0; t < WIN; ++t) { v[t] = fmaf(P, CK[t], v[t]); P *= B; }
        #pragma unroll
        for (int t = 0; t < WIN; ++t) h[wv][i + t][lane] = v[t];
    }

    __syncthreads();

    // Per-wave column reduce: lane j sums 64 lane-columns at row j+R.
    // bank = ((j+R)*64 + j+cc) % 32 = (j+cc)%32: 2-way alias, free.
    {
        const int j = lane;
        float s = 0.0f;
        #pragma unroll
        for (int cc = 0; cc < 64; ++cc)
            s += h[wv][R + j][(j + cc) & 63];
        part[wv][j] = s;
    }
    __syncthreads();
    if (threadIdx.x < BINS) {
        const int j = threadIdx.x;
        part_out[blk * BINS + j] = part[0][j] + part[1][j];  // plain store
    }
}

__global__ __launch_bounds__(NCH * 64) void final_kernel(
        const float* __restrict__ part, float* __restrict__ out) {
    const int w    = threadIdx.x >> 6;   // 0..11 -> (b,c) channel
    const int lane = threadIdx.x & 63;   // bin

    // sum the 32 chunk-partials for pred and target (coalesced per c).
    float ph = 0.0f, th = 0.0f;
    #pragma unroll
    for (int c = 0; c < BPC; ++c) {
        ph += part[(w * BPC + c) * BINS + lane];
        th += part[((NCH + w) * BPC + c) * BINS + lane];
    }

    // inclusive scan over bins (wave64 shfl_up)
    float ps = ph, ts = th;
    #pragma unroll
    for (int d = 1; d < 64; d <<= 1) {
        float a = __shfl_up(ps, d, 64);
        float b = __shfl_up(ts, d, 64);
        if (lane >= d) { ps += a; ts += b; }
    }
    float ptot = __shfl(ps, 63, 64);
    float ttot = __shfl(ts, 63, 64);
    float pc = ps / (ptot + 1e-8f);
    float tc = ts / (ttot + 1e-8f);
    float dv = fabsf(pc - tc);

    // wave reduce
    #pragma unroll
    for (int k = 32; k >= 1; k >>= 1) dv += __shfl_xor(dv, k, 64);

    __shared__ float warr[NCH];
    if (lane == 0) warr[w] = dv;
    __syncthreads();
    if (threadIdx.x == 0) {
        float s = 0.0f;
        #pragma unroll
        for (int i = 0; i < NCH; ++i) s += warr[i];
        out[0] = s / (float)(NCH * BINS);
    }
}

extern "C" void kernel_launch(void* const* d_in, const int* in_sizes, int n_in,
                              void* d_out, int out_size, void* d_ws, size_t ws_size,
                              hipStream_t stream) {
    const float* pred   = (const float*)d_in[0];
    const float* target = (const float*)d_in[1];
    float* part = (float*)d_ws;          // 768*64 floats = 196 KB partials
    float* out  = (float*)d_out;

    hist_kernel<<<dim3(2 * NCH * BPC), dim3(THREADS), 0, stream>>>(
        pred, target, part);
    final_kernel<<<dim3(1), dim3(NCH * 64), 0, stream>>>(part, out);
}